// Round 1
// baseline (122.344 us; speedup 1.0000x reference)
//
#include <hip/hip_runtime.h>

#define N_PTS 8192
#define D_DIM 256
#define BN 256              // set1 rows per block
#define BM 256              // set2 rows per block
#define BK 64
#define INF_BITS 0x7F800000u

typedef __attribute__((ext_vector_type(8))) short short8;
typedef __attribute__((ext_vector_type(4))) float f32x4;

// async global->LDS, 16B/lane; LDS dest = wave-uniform base + lane*16
__device__ __forceinline__ void gload_lds16(const ushort* g, ushort* l) {
    __builtin_amdgcn_global_load_lds(
        (const __attribute__((address_space(1))) void*)g,
        (__attribute__((address_space(3))) void*)l, 16, 0, 0);
}

__device__ __forceinline__ ushort f2bf(float x) {
    unsigned u = __float_as_uint(x);
    return (ushort)((u + 0x7FFFu + ((u >> 16) & 1u)) >> 16);  // RNE, no NaNs here
}

// ---- fused prep: bf16 convert + row sqnorms (fp32 exact) + INF init ----
__global__ void prep_kernel(const float* __restrict__ s1, const float* __restrict__ s2,
                            ushort* __restrict__ b1, ushort* __restrict__ b2,
                            float* __restrict__ sq1, float* __restrict__ sq2,
                            unsigned* __restrict__ rowmin2, unsigned* __restrict__ colmin2) {
    const int half = N_PTS * D_DIM;
    int t = blockIdx.x * 256 + threadIdx.x;
    int e = t * 8;
    bool first = e < half;
    const float* src = first ? s1 : s2;
    ushort* dst = first ? b1 : b2;
    int off = first ? e : e - half;
    float4 v0 = *(const float4*)(src + off);
    float4 v1 = *(const float4*)(src + off + 4);
    float s = v0.x * v0.x + v0.y * v0.y + v0.z * v0.z + v0.w * v0.w
            + v1.x * v1.x + v1.y * v1.y + v1.z * v1.z + v1.w * v1.w;
    ushort4 o0 = { f2bf(v0.x), f2bf(v0.y), f2bf(v0.z), f2bf(v0.w) };
    ushort4 o1 = { f2bf(v1.x), f2bf(v1.y), f2bf(v1.z), f2bf(v1.w) };
    *(ushort4*)(dst + off)     = o0;
    *(ushort4*)(dst + off + 4) = o1;
    // one row = 32 consecutive threads; xor masks <=16 stay inside the half-wave
    #pragma unroll
    for (int m = 1; m <= 16; m <<= 1) s += __shfl_xor(s, m, 64);
    int sub = threadIdx.x & 31;
    int row = off >> 8;
    if (sub == 0) (first ? sq1 : sq2)[row] = s;
    if (sub == 1) (first ? rowmin2 : colmin2)[row] = INF_BITS;
}

// stage one 256-row x BK tile (256 rows x 8 chunks of 16B) with 512 threads.
// XOR-swizzle: LDS slot (row, sc) holds global chunk (row, sc ^ (row&7)).
__device__ __forceinline__ void stage256(const ushort* __restrict__ g, ushort* l, int tid) {
    #pragma unroll
    for (int r = 0; r < 4; r++) {
        int idx = r * 512 + tid;          // chunk slot 0..2047
        int row = idx >> 3;
        int gc  = (idx & 7) ^ (row & 7);  // inverse-swizzled GLOBAL source (G21)
        gload_lds16(g + (size_t)row * D_DIM + gc * 8, &l[(idx & ~63) * 8]);
    }
}

// ---- MFMA gram + fused d^2 + row/col min, 256^2 8-wave 4-phase/K-tile schedule ----
// T3+T4: raw s_barrier + counted waits (no __syncthreads vmcnt(0) drain in main loop),
// stage of tile t+1 issued during tile t's phases 0-1, waited 2+ phases later.
// T5: setprio(1) around each 16-MFMA cluster.
__global__ __launch_bounds__(512, 2) void tile_kernel(
    const ushort* __restrict__ B1, const ushort* __restrict__ B2,
    const float* __restrict__ sq1, const float* __restrict__ sq2,
    unsigned* __restrict__ rowmin2, unsigned* __restrict__ colmin2) {
    __shared__ ushort As[2][BN * BK] __attribute__((aligned(16)));   // 2 x 32 KB
    __shared__ ushort Bs[2][BM * BK] __attribute__((aligned(16)));   // 2 x 32 KB
    __shared__ unsigned rs[BN];
    __shared__ unsigned cs[BM];

    const int tid  = threadIdx.x;
    const int lane = tid & 63;
    const int w    = tid >> 6;          // 8 waves: 2 (n) x 4 (m)
    const int quad = lane >> 4;
    const int c    = lane & 15;
    const int n_off = (w >> 2) * 128;   // wave tile: 128(n) x 64(m)
    const int m_off = (w & 3) * 64;
    const int n0 = blockIdx.y * BN;
    const int m0 = blockIdx.x * BM;

    if (tid < BN) rs[tid] = INF_BITS;
    else          cs[tid - BN] = INF_BITS;

    f32x4 acc[8][4];
    #pragma unroll
    for (int ti = 0; ti < 8; ti++)
        #pragma unroll
        for (int tj = 0; tj < 4; tj++) acc[ti][tj] = (f32x4){0.f, 0.f, 0.f, 0.f};

    const ushort* gA = B1 + (size_t)n0 * D_DIM;
    const ushort* gB = B2 + (size_t)m0 * D_DIM;

    // prologue: stage tile 0 into buf0 (8 loads/thread), drain once, barrier
    stage256(gA, As[0], tid);
    stage256(gB, Bs[0], tid);
    asm volatile("s_waitcnt vmcnt(0)" ::: "memory");
    __builtin_amdgcn_s_barrier();

    #pragma unroll 4
    for (int t = 0; t < 4; ++t) {
        const ushort* cA = As[t & 1];
        const ushort* cB = Bs[t & 1];
        #pragma unroll
        for (int p = 0; p < 4; ++p) {
            const int kk = p >> 1;      // K-half of this tile
            const int h  = p & 1;       // n-half of the wave tile
            short8 a[4], b[4];
            #pragma unroll
            for (int i = 0; i < 4; i++) {
                int row = n_off + (h * 4 + i) * 16 + c;
                int ch  = (kk * 4 + quad) ^ (row & 7);
                a[i] = *(const short8*)&cA[row * BK + ch * 8];
            }
            #pragma unroll
            for (int j = 0; j < 4; j++) {
                int row = m_off + j * 16 + c;
                int ch  = (kk * 4 + quad) ^ (row & 7);
                b[j] = *(const short8*)&cB[row * BK + ch * 8];
            }
            // issue next tile's stage early (phases 0-1) so the end-of-tile wait
            // lands on long-completed loads (L2-resident, ~200-300 cyc)
            if (t < 3 && p == 0) stage256(gA + (t + 1) * BK, As[(t + 1) & 1], tid);
            if (t < 3 && p == 1) stage256(gB + (t + 1) * BK, Bs[(t + 1) & 1], tid);

            __builtin_amdgcn_s_barrier();
            asm volatile("s_waitcnt lgkmcnt(0)" ::: "memory");
            __builtin_amdgcn_s_setprio(1);
            #pragma unroll
            for (int i = 0; i < 4; i++)
                #pragma unroll
                for (int j = 0; j < 4; j++)
                    acc[h * 4 + i][j] = __builtin_amdgcn_mfma_f32_16x16x32_bf16(
                        a[i], b[j], acc[h * 4 + i][j], 0, 0, 0);
            __builtin_amdgcn_s_setprio(0);
            // once per K-tile: ensure next tile's buffer is fully landed in every
            // wave before any wave crosses into its ds_reads
            if (p == 3 && t < 3) asm volatile("s_waitcnt vmcnt(0)" ::: "memory");
            __builtin_amdgcn_s_barrier();
        }
    }

    // epilogue: d2 = sq1[n]+sq2[m]-2*gram; C/D: col(m)=lane&15, row(n)=quad*4+reg
    float sqm[4];
    #pragma unroll
    for (int tj = 0; tj < 4; tj++) sqm[tj] = sq2[m0 + m_off + tj * 16 + c];
    float cmin[4];
    #pragma unroll
    for (int tj = 0; tj < 4; tj++) cmin[tj] = __uint_as_float(INF_BITS);

    #pragma unroll
    for (int ti = 0; ti < 8; ti++) {
        float4 sqn = *(const float4*)&sq1[n0 + n_off + ti * 16 + quad * 4];
        float rmin[4] = { __uint_as_float(INF_BITS), __uint_as_float(INF_BITS),
                          __uint_as_float(INF_BITS), __uint_as_float(INF_BITS) };
        #pragma unroll
        for (int tj = 0; tj < 4; tj++) {
            float sn[4] = { sqn.x, sqn.y, sqn.z, sqn.w };
            #pragma unroll
            for (int r = 0; r < 4; r++) {
                float d2 = fmaxf(sn[r] + sqm[tj] - 2.f * acc[ti][tj][r], 0.f);
                rmin[r]  = fminf(rmin[r], d2);
                cmin[tj] = fminf(cmin[tj], d2);
            }
        }
        // reduce row-mins over the 16 lanes (c) of the quad
        #pragma unroll
        for (int m = 1; m <= 8; m <<= 1)
            #pragma unroll
            for (int r = 0; r < 4; r++)
                rmin[r] = fminf(rmin[r], __shfl_xor(rmin[r], m, 64));
        if (c == 0) {
            #pragma unroll
            for (int r = 0; r < 4; r++)
                atomicMin(&rs[n_off + ti * 16 + quad * 4 + r], __float_as_uint(rmin[r]));
        }
    }
    // reduce col-mins over the 4 quads
    #pragma unroll
    for (int m = 16; m <= 32; m <<= 1)
        #pragma unroll
        for (int tj = 0; tj < 4; tj++)
            cmin[tj] = fminf(cmin[tj], __shfl_xor(cmin[tj], m, 64));
    if (quad == 0) {
        #pragma unroll
        for (int tj = 0; tj < 4; tj++)
            atomicMin(&cs[m_off + tj * 16 + c], __float_as_uint(cmin[tj]));
    }
    __syncthreads();

    if (tid < BN) atomicMin(&rowmin2[n0 + tid], rs[tid]);
    else          atomicMin(&colmin2[m0 + tid - BN], cs[tid - BN]);
}

// ---- final: mean(sqrt(min d^2)) over rowmin2||colmin2 (contiguous 2*N_PTS) ----
__global__ __launch_bounds__(1024) void reduce_kernel(const unsigned* __restrict__ mins,
                                                      float* __restrict__ out) {
    int tid = threadIdx.x;
    uint4 v[4];
    #pragma unroll
    for (int j = 0; j < 4; j++) v[j] = ((const uint4*)mins)[j * 1024 + tid];
    float s = 0.f;
    #pragma unroll
    for (int j = 0; j < 4; j++)
        s += sqrtf(__uint_as_float(v[j].x)) + sqrtf(__uint_as_float(v[j].y))
           + sqrtf(__uint_as_float(v[j].z)) + sqrtf(__uint_as_float(v[j].w));
    #pragma unroll
    for (int m = 32; m > 0; m >>= 1) s += __shfl_xor(s, m, 64);
    __shared__ float ws[16];
    int lane = tid & 63, wv = tid >> 6;
    if (lane == 0) ws[wv] = s;
    __syncthreads();
    if (tid < 16) {
        float t = ws[tid];
        #pragma unroll
        for (int m = 8; m > 0; m >>= 1) t += __shfl_xor(t, m, 64);
        if (tid == 0) out[0] = t / (float)N_PTS;
    }
}

extern "C" void kernel_launch(void* const* d_in, const int* in_sizes, int n_in,
                              void* d_out, int out_size, void* d_ws, size_t ws_size,
                              hipStream_t stream) {
    const float* set1 = (const float*)d_in[0];
    const float* set2 = (const float*)d_in[1];
    float* out = (float*)d_out;

    // workspace: rowmin2[8192] | colmin2[8192] (contiguous!) | sq1 | sq2 | pad | b1 | b2
    unsigned* rowmin2 = (unsigned*)d_ws;
    unsigned* colmin2 = rowmin2 + N_PTS;
    float* sq1 = (float*)(colmin2 + N_PTS);
    float* sq2 = sq1 + N_PTS;
    ushort* b1 = (ushort*)((char*)d_ws + 128 * 1024);       // 256B-aligned, past headers
    ushort* b2 = b1 + (size_t)N_PTS * D_DIM;

    prep_kernel<<<(2 * N_PTS * D_DIM) / (256 * 8), 256, 0, stream>>>(
        set1, set2, b1, b2, sq1, sq2, rowmin2, colmin2);
    tile_kernel<<<dim3(N_PTS / BM, N_PTS / BN), 512, 0, stream>>>(
        b1, b2, sq1, sq2, rowmin2, colmin2);
    reduce_kernel<<<1, 1024, 0, stream>>>(rowmin2, out);
}